// Round 18
// baseline (787.659 us; speedup 1.0000x reference)
//
#include <hip/hip_runtime.h>

#define NTOK 49
#define CDIM 192
#define NHEAD 6
#define HDIM 32

typedef float f32x4 __attribute__((ext_vector_type(4), may_alias));
typedef float f32x4u __attribute__((ext_vector_type(4), may_alias, aligned(4)));
typedef short b16x8 __attribute__((ext_vector_type(8), may_alias));
typedef short b16x4 __attribute__((ext_vector_type(4), may_alias));

#define LOG2E 1.4426950408889634f

__device__ __forceinline__ f32x4 MFMA(b16x8 a, b16x8 b, f32x4 c) {
  return __builtin_amdgcn_mfma_f32_16x16x32_bf16(a, b, c, 0, 0, 0);
}

__device__ __forceinline__ short f2bf(float f) {
  unsigned u = __builtin_bit_cast(unsigned, f);
  u += 0x7FFFu + ((u >> 16) & 1u);  // round-to-nearest-even
  return (short)(u >> 16);
}

// raw v_exp_f32 = 2^x (logits are pre-scaled by log2e end-to-end)
__device__ __forceinline__ float exp2_(float x) {
  float r;
  asm("v_exp_f32 %0, %1" : "=v"(r) : "v"(x));
  return r;
}
__device__ __forceinline__ float rcp_(float x) {
  float r;
  asm("v_rcp_f32 %0, %1" : "=v"(r) : "v"(x));
  return r;
}

// XOR swizzle for [64][192] bf16 tiles (granule 8 shorts = 16B), bijective.
__device__ __forceinline__ int swz(int row, int col) {
  return row * CDIM + (col ^ ((row & 7) << 3));
}
// [16][32] P scratch: mix row bits 0-1 and 2-3 (R8/R15-verified conflict-safe).
__device__ __forceinline__ int ps(int r, int c) {
  return r * 32 + (c ^ ((((r & 3) ^ ((r >> 2) & 3)) & 3) << 3));
}

// ---- prep 1: fp32 weights -> bf16 ws. Wq pre-scaled by D^-0.5 * log2e ----
__global__ void prep_w(const float* __restrict__ Wq, const float* __restrict__ Wkv,
                       const float* __restrict__ Wo, short* __restrict__ wsW) {
  const float scale = 0.17677669529663687f * LOG2E;
  int i = blockIdx.x * 256 + threadIdx.x;
  if (i >= 147456) return;
  float v;
  if (i < 36864)        v = Wq[i] * scale;
  else if (i < 110592)  v = Wkv[i - 36864];
  else                  v = Wo[i - 110592];
  wsW[i] = f2bf(v);
}

// ---- prep 2: rel-pos-bias*log2e [6][49][64] f32; k-pad (49..63) = -1e9 ----
__global__ void prep_bias(const float* __restrict__ rpb, float* __restrict__ bias_t) {
  int idx = blockIdx.x * 256 + threadIdx.x;
  if (idx >= NHEAD * NTOK * 64) return;
  int k = idx & 63;
  int q = (idx >> 6) % NTOK;
  int h = idx / (NTOK * 64);
  float v = -1e9f;  // exp2 underflows to 0 regardless of log2e scaling
  if (k < NTOK) {
    int ci = (q / 7) * 13 + (q % 7);
    int jj = 48 - k;
    int cj = (jj / 7) * 13 + (jj % 7);
    v = rpb[(ci + cj) * NHEAD + h] * LOG2E;
  }
  bias_t[idx] = v;
}

// ============================================================================
// Fused window-MSA — R15/R17 champion (784 us, zero spill, VGPR=64) with the
// last register-neutral lever: softmax critical-chain micro-opts.
//   - logits pre-scaled by log2e (Wq/bq prescale, bias table, mask loads) ->
//     exp = single v_exp_f32 (saves 16 VALU/head on the chain)
//   - max reduce as v_max3-fusable triples (dep depth 15 -> 3)
//   - sum reduce pairwise tree (dep depth 16 -> 4); 1/sum via v_rcp_f32
//
// Structural constraint (R2-R17 evidence): live set needs ~120 total regs
// (forcing less -> 1-1.6 GB spill storms, R6/R7/R16); at VGPR 64 + AGPR 64
// the wave cap is 4 waves/SIMD (waves/SIMD ~ 512/(VGPRgranule+AGPR)), so TLP
// is pinned at 16 waves/CU; +4 VGPR halves occupancy (R13). Kernel split
// (R9), multi-window blocks (R16), forced occupancy (R6/R7) all regressed.
// HBM traffic is minimal (FETCH ~309 MB, WRITE = 301 MB = output exactly).
// ============================================================================
__global__ __attribute__((amdgpu_flat_work_group_size(512, 512),
                          amdgpu_waves_per_eu(3))) void wmsa_kernel(
    const float* __restrict__ qg, const float* __restrict__ kvg,
    const float* __restrict__ maskg, const float* __restrict__ bq,
    const float* __restrict__ bkv, const float* __restrict__ bo,
    const short* __restrict__ wsW, const float* __restrict__ bias_t,
    float* __restrict__ outg, int nW) {
  __shared__ short lds[37632];     // 75264 B
  short* SH = lds;                 // [64][192] swizzled
  short* VT = lds + 12288;         // [192][68] vhT[c][token]
  short* KH = lds + 25344;         // [64][192] swizzled
  float* BF = (float*)lds;         // epilogue bounce [49][204] f32 (40 KB)

  const int b = blockIdx.x;
  const int tid = threadIdx.x;
  const int w = tid >> 6;          // wave 0..7
  const int lane = tid & 63;
  const int l15 = lane & 15;
  const int lg = lane >> 4;
  const int R = w >> 1, hw = w & 1, h0 = hw * 3;
  const float scale = 0.17677669529663687f * LOG2E;
  const f32x4 zero4 = {0.f, 0.f, 0.f, 0.f};

  const short* WqB = wsW;
  const short* WkvB = wsW + 36864;
  const short* WoB = wsW + 110592;

  const float* qsrc = qg + (size_t)b * (NTOK * CDIM);
  const float* kvsrc = kvg + (size_t)b * (NTOK * CDIM);

  const int qrow = R * 16 + l15;
  const int qc = qrow > 48 ? 48 : qrow;  // pad lanes -> row 48 (outputs unused)

  // ---- issue q and kv loads up front (HBM latency hidden under staging+q-proj) ----
  f32x4 qv[6], kvreg[6];
#pragma unroll
  for (int it = 0; it < 6; ++it) {
    int idx = tid + it * 512;
    int r = idx / 48, c4 = idx % 48;
    qv[it] = (r < NTOK) ? *(const f32x4*)(qsrc + r * CDIM + c4 * 4) : zero4;
  }
#pragma unroll
  for (int it = 0; it < 6; ++it) {
    int idx = tid + it * 512;
    int r = idx / 48, c4 = idx % 48;
    kvreg[it] = (r < NTOK) ? *(const f32x4*)(kvsrc + r * CDIM + c4 * 4) : zero4;
  }
  // ---- stage q -> SH bf16 (rows 49..63 zero) ----
#pragma unroll
  for (int it = 0; it < 6; ++it) {
    int idx = tid + it * 512;
    int r = idx / 48, c4 = idx % 48;
    b16x4 o = {f2bf(qv[it][0]), f2bf(qv[it][1]), f2bf(qv[it][2]), f2bf(qv[it][3])};
    *(b16x4*)(SH + swz(r, c4 * 4)) = o;
  }
  __syncthreads();  // B1: q staged

  // ---- q projection: wave computes exactly its own attention q-tile ----
  f32x4 qacc[6];
#pragma unroll
  for (int t = 0; t < 6; ++t) qacc[t] = zero4;
  {
    b16x8 aq6[6];
#pragma unroll
    for (int kk = 0; kk < 6; ++kk)
      aq6[kk] = *(const b16x8*)(SH + swz(R * 16 + l15, kk * 32 + lg * 8));
#pragma unroll
    for (int t = 0; t < 6; ++t) {
      const int col = (hw * 6 + t) * 16 + l15;
#pragma unroll
      for (int kk = 0; kk < 6; ++kk) {
        b16x8 bw = *(const b16x8*)(WqB + col * CDIM + kk * 32 + lg * 8);
        qacc[t] = MFMA(aq6[kk], bw, qacc[t]);
      }
    }
  }
  // ---- qh -> KH bounce (KH dead until kv-proj; own-wave RAW ordered ->
  // the aq readback needs NO barrier) ----
#pragma unroll
  for (int t = 0; t < 6; ++t) {
    const int col = (hw * 6 + t) * 16 + l15;
    const float bias = bq[col] * scale;
#pragma unroll
    for (int r = 0; r < 4; ++r)
      KH[swz(R * 16 + lg * 4 + r, hw * 96 + t * 16 + l15)] = f2bf(qacc[t][r] + bias);
  }
  b16x8 aq[3];
#pragma unroll
  for (int hh = 0; hh < 3; ++hh)
    aq[hh] = *(const b16x8*)(KH + swz(R * 16 + l15, hw * 96 + hh * 32 + lg * 8));
  __syncthreads();  // B2: q-proj SH reads done (SH free); aq readbacks done

  // ---- stage kv (from regs) -> SH ----
#pragma unroll
  for (int it = 0; it < 6; ++it) {
    int idx = tid + it * 512;
    int r = idx / 48, c4 = idx % 48;
    b16x4 o = {f2bf(kvreg[it][0]), f2bf(kvreg[it][1]), f2bf(kvreg[it][2]),
               f2bf(kvreg[it][3])};
    *(b16x4*)(SH + swz(r, c4 * 4)) = o;
  }
  __syncthreads();  // B3: kv staged

  // ---- kv projection: 24 col-tiles, wave w -> nt = w*3 + {0,1,2} ----
#pragma unroll
  for (int jj = 0; jj < 3; ++jj) {
    const int nt = w * 3 + jj;
    const int col = nt * 16 + l15;  // 0..383
    f32x4 acc[4];
#pragma unroll
    for (int m = 0; m < 4; ++m) acc[m] = zero4;
#pragma unroll
    for (int kk = 0; kk < 6; ++kk) {
      b16x8 bw = *(const b16x8*)(WkvB + col * CDIM + kk * 32 + lg * 8);
#pragma unroll
      for (int m = 0; m < 4; ++m) {
        b16x8 a = *(const b16x8*)(SH + swz(m * 16 + l15, kk * 32 + lg * 8));
        acc[m] = MFMA(a, bw, acc[m]);
      }
    }
    const float bias = bkv[col];
    if (col < CDIM) {  // K half -> KH[token][col]
#pragma unroll
      for (int m = 0; m < 4; ++m)
#pragma unroll
        for (int r = 0; r < 4; ++r)
          KH[swz(m * 16 + lg * 4 + r, col)] = f2bf(acc[m][r] + bias);
    } else {  // V half -> VT[c][token]
      const int c = col - CDIM;
#pragma unroll
      for (int m = 0; m < 4; ++m) {
        b16x4 o = {f2bf(acc[m][0] + bias), f2bf(acc[m][1] + bias),
                   f2bf(acc[m][2] + bias), f2bf(acc[m][3] + bias)};
        *(b16x4*)(VT + c * 68 + m * 16 + lg * 4) = o;
      }
    }
  }
  __syncthreads();  // B4: kh/vT ready; SH kv dead -> P scratch

  // ---- attention (swapped QK, in-lane softmax): lane l15 owns q-row qc ----
  // mask hoisted and pre-scaled by log2e (exp2 path)
  const float* maskw = maskg + (size_t)(b % nW) * (NTOK * NTOK);
  f32x4 maskv[3];
#pragma unroll
  for (int nt = 0; nt < 3; ++nt) {
    f32x4 t = *(const f32x4u*)(maskw + qc * NTOK + nt * 16 + lg * 4);
#pragma unroll
    for (int rr = 0; rr < 4; ++rr) maskv[nt][rr] = t[rr] * LOG2E;
  }
  const float mask48 = (lg == 0) ? maskw[qc * NTOK + 48] * LOG2E : 0.f;

  f32x4 xh[3][2];
#pragma unroll
  for (int hh = 0; hh < 3; ++hh) {
    xh[hh][0] = zero4;
    xh[hh][1] = zero4;
  }
#pragma unroll
  for (int hh = 0; hh < 3; ++hh) {
    const int h = h0 + hh;
    f32x4 Ls[4];
    __builtin_amdgcn_s_setprio(1);
#pragma unroll
    for (int nt = 0; nt < 4; ++nt) {
      b16x8 bk = *(const b16x8*)(KH + swz(nt * 16 + l15, h * 32 + lg * 8));
      Ls[nt] = MFMA(bk, aq[hh], zero4);  // swapped: D col = q-row l15
    }
    __builtin_amdgcn_s_setprio(0);
    // bias (k-padded -1e9, *log2e) + window mask (*log2e), no branches
    const float* bt = bias_t + (h * NTOK + qc) * 64;
#pragma unroll
    for (int nt = 0; nt < 4; ++nt) {
      f32x4 bb = *(const f32x4*)(bt + nt * 16 + lg * 4);
#pragma unroll
      for (int rr = 0; rr < 4; ++rr) Ls[nt][rr] += bb[rr];
    }
#pragma unroll
    for (int nt = 0; nt < 3; ++nt)
#pragma unroll
      for (int rr = 0; rr < 4; ++rr) Ls[nt][rr] += maskv[nt][rr];
    Ls[3][0] += mask48;  // k=48 (lg==0); other lanes add 0, k>=49 has -1e9 bias

    // in-lane softmax, exp2 domain. max: v_max3-fusable triples, depth 3.
    float t0 = fmaxf(fmaxf(Ls[0][0], Ls[0][1]), Ls[0][2]);
    float t1 = fmaxf(fmaxf(Ls[0][3], Ls[1][0]), Ls[1][1]);
    float t2 = fmaxf(fmaxf(Ls[1][2], Ls[1][3]), Ls[2][0]);
    float t3 = fmaxf(fmaxf(Ls[2][1], Ls[2][2]), Ls[2][3]);
    float t4 = fmaxf(fmaxf(Ls[3][0], Ls[3][1]), Ls[3][2]);
    float mx = fmaxf(fmaxf(fmaxf(t0, t1), t2), fmaxf(fmaxf(t3, t4), Ls[3][3]));
    mx = fmaxf(mx, __shfl_xor(mx, 16));
    mx = fmaxf(mx, __shfl_xor(mx, 32));
#pragma unroll
    for (int nt = 0; nt < 4; ++nt)
#pragma unroll
      for (int rr = 0; rr < 4; ++rr) Ls[nt][rr] = exp2_(Ls[nt][rr] - mx);
    // pairwise sum tree (depth 4 vs serial 16)
    float s0 = (Ls[0][0] + Ls[0][1]) + (Ls[0][2] + Ls[0][3]);
    float s1 = (Ls[1][0] + Ls[1][1]) + (Ls[1][2] + Ls[1][3]);
    float s2 = (Ls[2][0] + Ls[2][1]) + (Ls[2][2] + Ls[2][3]);
    float s3 = (Ls[3][0] + Ls[3][1]) + (Ls[3][2] + Ls[3][3]);
    float sum = (s0 + s1) + (s2 + s3);
    sum += __shfl_xor(sum, 16);
    sum += __shfl_xor(sum, 32);
    const float inv = rcp_(sum);  // 1-ulp rcp; P is bf16-bound

    // P -> per-wave scratch in dead-SH (ps swizzle), two 32-k halves; PV
    short* Pscr = SH + w * 512;
    b16x8 ap[2];
#pragma unroll
    for (int kkh = 0; kkh < 2; ++kkh) {
#pragma unroll
      for (int nth = 0; nth < 2; ++nth) {
        const int nt = 2 * kkh + nth;
        b16x4 o = {f2bf(Ls[nt][0] * inv), f2bf(Ls[nt][1] * inv),
                   f2bf(Ls[nt][2] * inv), f2bf(Ls[nt][3] * inv)};
        *(b16x4*)(Pscr + ps(l15, nth * 16 + lg * 4)) = o;
      }
      ap[kkh] = *(const b16x8*)(Pscr + ps(l15, lg * 8));
    }
    __builtin_amdgcn_s_setprio(1);
#pragma unroll
    for (int kkh = 0; kkh < 2; ++kkh)
#pragma unroll
      for (int nv = 0; nv < 2; ++nv) {
        b16x8 bv = *(const b16x8*)(VT + (h * 32 + nv * 16 + l15) * 68 + kkh * 32 + lg * 8);
        xh[hh][nv] = MFMA(ap[kkh], bv, xh[hh][nv]);
      }
    __builtin_amdgcn_s_setprio(0);
  }
  __syncthreads();  // B5: all KH/VT/SH-P reads done
  // ---- x -> KH ----
#pragma unroll
  for (int hh = 0; hh < 3; ++hh)
#pragma unroll
    for (int nv = 0; nv < 2; ++nv)
#pragma unroll
      for (int r = 0; r < 4; ++r)
        KH[swz(R * 16 + lg * 4 + r, (h0 + hh) * 32 + nv * 16 + l15)] =
            f2bf(xh[hh][nv][r]);
  __syncthreads();  // B6: x ready (SH, VT dead -> bounce region)

  // ---- output projection -> f32 bounce (stride 204) ----
#pragma unroll
  for (int t = 0; t < 6; ++t) {
    const int pid = w * 6 + t;
    const int j = pid >> 2, m = pid & 3;
    const int col = j * 16 + l15;
    f32x4 oacc = zero4;
#pragma unroll
    for (int kk = 0; kk < 6; ++kk) {
      b16x8 a = *(const b16x8*)(KH + swz(m * 16 + l15, kk * 32 + lg * 8));
      b16x8 bw = *(const b16x8*)(WoB + col * CDIM + kk * 32 + lg * 8);
      oacc = MFMA(a, bw, oacc);
    }
    const float bias = bo[col];
#pragma unroll
    for (int r = 0; r < 4; ++r) {
      const int row = m * 16 + lg * 4 + r;
      if (row < NTOK) BF[row * 204 + col] = oacc[r] + bias;
    }
  }
  __syncthreads();  // B7: bounce ready

  // ---- fully coalesced output stores (16B/lane contiguous) ----
  float* dst = outg + (size_t)b * (NTOK * CDIM);
#pragma unroll
  for (int t = 0; t < 5; ++t) {
    int idx = tid + t * 512;
    if (idx < NTOK * 48) {
      int row = idx / 48, c4 = idx % 48;
      f32x4 v = *(const f32x4*)(BF + row * 204 + c4 * 4);
      *(f32x4*)(dst + row * CDIM + c4 * 4) = v;
    }
  }
}

extern "C" void kernel_launch(void* const* d_in, const int* in_sizes, int n_in,
                              void* d_out, int out_size, void* d_ws, size_t ws_size,
                              hipStream_t stream) {
  const float* q = (const float*)d_in[0];
  const float* kv = (const float*)d_in[1];
  const float* mask = (const float*)d_in[2];
  const float* Wq = (const float*)d_in[3];
  const float* bq = (const float*)d_in[4];
  const float* Wkv = (const float*)d_in[5];
  const float* bkv = (const float*)d_in[6];
  const float* Wo = (const float*)d_in[7];
  const float* bo = (const float*)d_in[8];
  const float* rpb = (const float*)d_in[9];
  short* wsW = (short*)d_ws;
  float* bias_t = (float*)((char*)d_ws + 294912);  // [6][49][64] f32, 75264 B

  const int B = in_sizes[0] / (NTOK * CDIM);
  const int nW = in_sizes[2] / (NTOK * NTOK);

  prep_w<<<576, 256, 0, stream>>>(Wq, Wkv, Wo, wsW);
  prep_bias<<<(NHEAD * NTOK * 64 + 255) / 256, 256, 0, stream>>>(rpb, bias_t);
  wmsa_kernel<<<B, 512, 0, stream>>>(q, kv, mask, bq, bkv, bo, wsW, bias_t,
                                     (float*)d_out, nW);
}

// Round 19
// 781.484 us; speedup vs baseline: 1.0079x; 1.0079x over previous
//
#include <hip/hip_runtime.h>

#define NTOK 49
#define CDIM 192
#define NHEAD 6
#define HDIM 32

typedef float f32x4 __attribute__((ext_vector_type(4), may_alias));
typedef float f32x4u __attribute__((ext_vector_type(4), may_alias, aligned(4)));
typedef short b16x8 __attribute__((ext_vector_type(8), may_alias));
typedef short b16x4 __attribute__((ext_vector_type(4), may_alias));

__device__ __forceinline__ f32x4 MFMA(b16x8 a, b16x8 b, f32x4 c) {
  return __builtin_amdgcn_mfma_f32_16x16x32_bf16(a, b, c, 0, 0, 0);
}

__device__ __forceinline__ short f2bf(float f) {
  unsigned u = __builtin_bit_cast(unsigned, f);
  u += 0x7FFFu + ((u >> 16) & 1u);  // round-to-nearest-even
  return (short)(u >> 16);
}

// XOR swizzle for [64][192] bf16 tiles (granule 8 shorts = 16B), bijective.
__device__ __forceinline__ int swz(int row, int col) {
  return row * CDIM + (col ^ ((row & 7) << 3));
}
// [16][32] P scratch: mix row bits 0-1 and 2-3 (R8/R15-verified conflict-safe).
__device__ __forceinline__ int ps(int r, int c) {
  return r * 32 + (c ^ ((((r & 3) ^ ((r >> 2) & 3)) & 3) << 3));
}

// ---- merged prep: weights -> bf16 (Wq pre-scaled by D^-0.5) AND rel-pos
// bias table [6][49][64] f32 with k-pad (49..63) = -1e9 (bakes the k-range
// mask). One dispatch instead of two.
__global__ void prep_all(const float* __restrict__ Wq, const float* __restrict__ Wkv,
                         const float* __restrict__ Wo, const float* __restrict__ rpb,
                         short* __restrict__ wsW, float* __restrict__ bias_t) {
  int i = blockIdx.x * 256 + threadIdx.x;
  if (i < 147456) {
    const float scale = 0.17677669529663687f;
    float v;
    if (i < 36864)        v = Wq[i] * scale;
    else if (i < 110592)  v = Wkv[i - 36864];
    else                  v = Wo[i - 110592];
    wsW[i] = f2bf(v);
  } else if (i < 147456 + NHEAD * NTOK * 64) {
    int idx = i - 147456;
    int k = idx & 63;
    int q = (idx >> 6) % NTOK;
    int h = idx / (NTOK * 64);
    float v = -1e9f;
    if (k < NTOK) {
      int ci = (q / 7) * 13 + (q % 7);
      int jj = 48 - k;
      int cj = (jj / 7) * 13 + (jj % 7);
      v = rpb[(ci + cj) * NHEAD + h];
    }
    bias_t[idx] = v;
  }
}

// ============================================================================
// Fused window-MSA — FINAL (R15/R17 champion, 784 us): 1 window/block,
// 8 waves, 7 barriers, zero spill, VGPR=64, occupancy 46% (= register cap).
//
// Structural constraint (R2-R18 evidence, 13 measured alternatives):
// - Live set genuinely needs ~120 total regs; forcing fewer (waves_per_eu
//   8/6, R6/R7; window loop, R16) -> 1-1.6 GB scratch-spill storms. At
//   VGPR 64 + AGPR 64 the wave cap is 4 waves/SIMD (occupancy law:
//   waves/SIMD ~ 512/(VGPRgranule+AGPR), fits R6-R13 data); +4 VGPR
//   crosses a granule and HALVES occupancy (R13).
// - TLP therefore pinned at 16 waves/CU; the 7-barrier serial phase chain
//   is latency-bound (MfmaUtil 8.6%, VALU 21-23%, HBM 9% - no throughput
//   roofline). Kernel split (R9, +HBM round trip), multi-window (R16),
//   setprio (R14, null), softmax chain micro-opts (R18, null) all failed
//   to move it. HBM traffic minimal: FETCH ~310 MB, WRITE = 301 MB = out.
//
// LDS (shorts): SH [0,12288) | VT [12288,25344) | KH [25344,37632).
// SH: q stage -> kv stage -> per-wave P scratch.  KH: qh bounce -> kh -> x.
// VT: vhT.  BF epilogue overlays SH+VT.
// Attention: swapped QK^T (mfma(K,Q)) -> lane owns q-row -> in-lane softmax
// (15 fmax + shfl 16,32); k>=49 masked by bias-table -1e9 padding.
// ============================================================================
__global__ __attribute__((amdgpu_flat_work_group_size(512, 512),
                          amdgpu_waves_per_eu(3))) void wmsa_kernel(
    const float* __restrict__ qg, const float* __restrict__ kvg,
    const float* __restrict__ maskg, const float* __restrict__ bq,
    const float* __restrict__ bkv, const float* __restrict__ bo,
    const short* __restrict__ wsW, const float* __restrict__ bias_t,
    float* __restrict__ outg, int nW) {
  __shared__ short lds[37632];     // 75264 B
  short* SH = lds;                 // [64][192] swizzled
  short* VT = lds + 12288;         // [192][68] vhT[c][token]
  short* KH = lds + 25344;         // [64][192] swizzled
  float* BF = (float*)lds;         // epilogue bounce [49][204] f32 (40 KB)

  const int b = blockIdx.x;
  const int tid = threadIdx.x;
  const int w = tid >> 6;          // wave 0..7
  const int lane = tid & 63;
  const int l15 = lane & 15;
  const int lg = lane >> 4;
  const int R = w >> 1, hw = w & 1, h0 = hw * 3;
  const float scale = 0.17677669529663687f;
  const f32x4 zero4 = {0.f, 0.f, 0.f, 0.f};

  const short* WqB = wsW;
  const short* WkvB = wsW + 36864;
  const short* WoB = wsW + 110592;

  const float* qsrc = qg + (size_t)b * (NTOK * CDIM);
  const float* kvsrc = kvg + (size_t)b * (NTOK * CDIM);

  const int qrow = R * 16 + l15;
  const int qc = qrow > 48 ? 48 : qrow;  // pad lanes -> row 48 (outputs unused)

  // ---- issue q and kv loads up front (HBM latency hidden under staging+q-proj) ----
  f32x4 qv[6], kvreg[6];
#pragma unroll
  for (int it = 0; it < 6; ++it) {
    int idx = tid + it * 512;
    int r = idx / 48, c4 = idx % 48;
    qv[it] = (r < NTOK) ? *(const f32x4*)(qsrc + r * CDIM + c4 * 4) : zero4;
  }
#pragma unroll
  for (int it = 0; it < 6; ++it) {
    int idx = tid + it * 512;
    int r = idx / 48, c4 = idx % 48;
    kvreg[it] = (r < NTOK) ? *(const f32x4*)(kvsrc + r * CDIM + c4 * 4) : zero4;
  }
  // ---- stage q -> SH bf16 (rows 49..63 zero) ----
#pragma unroll
  for (int it = 0; it < 6; ++it) {
    int idx = tid + it * 512;
    int r = idx / 48, c4 = idx % 48;
    b16x4 o = {f2bf(qv[it][0]), f2bf(qv[it][1]), f2bf(qv[it][2]), f2bf(qv[it][3])};
    *(b16x4*)(SH + swz(r, c4 * 4)) = o;
  }
  __syncthreads();  // B1: q staged

  // ---- q projection: wave computes exactly its own attention q-tile ----
  f32x4 qacc[6];
#pragma unroll
  for (int t = 0; t < 6; ++t) qacc[t] = zero4;
  {
    b16x8 aq6[6];
#pragma unroll
    for (int kk = 0; kk < 6; ++kk)
      aq6[kk] = *(const b16x8*)(SH + swz(R * 16 + l15, kk * 32 + lg * 8));
#pragma unroll
    for (int t = 0; t < 6; ++t) {
      const int col = (hw * 6 + t) * 16 + l15;
#pragma unroll
      for (int kk = 0; kk < 6; ++kk) {
        b16x8 bw = *(const b16x8*)(WqB + col * CDIM + kk * 32 + lg * 8);
        qacc[t] = MFMA(aq6[kk], bw, qacc[t]);
      }
    }
  }
  // ---- qh -> KH bounce (KH dead until kv-proj; own-wave RAW ordered ->
  // the aq readback needs NO barrier) ----
#pragma unroll
  for (int t = 0; t < 6; ++t) {
    const int col = (hw * 6 + t) * 16 + l15;
    const float bias = bq[col] * scale;
#pragma unroll
    for (int r = 0; r < 4; ++r)
      KH[swz(R * 16 + lg * 4 + r, hw * 96 + t * 16 + l15)] = f2bf(qacc[t][r] + bias);
  }
  b16x8 aq[3];
#pragma unroll
  for (int hh = 0; hh < 3; ++hh)
    aq[hh] = *(const b16x8*)(KH + swz(R * 16 + l15, hw * 96 + hh * 32 + lg * 8));
  __syncthreads();  // B2: q-proj SH reads done (SH free); aq readbacks done

  // ---- stage kv (from regs) -> SH ----
#pragma unroll
  for (int it = 0; it < 6; ++it) {
    int idx = tid + it * 512;
    int r = idx / 48, c4 = idx % 48;
    b16x4 o = {f2bf(kvreg[it][0]), f2bf(kvreg[it][1]), f2bf(kvreg[it][2]),
               f2bf(kvreg[it][3])};
    *(b16x4*)(SH + swz(r, c4 * 4)) = o;
  }
  __syncthreads();  // B3: kv staged

  // ---- kv projection: 24 col-tiles, wave w -> nt = w*3 + {0,1,2} ----
#pragma unroll
  for (int jj = 0; jj < 3; ++jj) {
    const int nt = w * 3 + jj;
    const int col = nt * 16 + l15;  // 0..383
    f32x4 acc[4];
#pragma unroll
    for (int m = 0; m < 4; ++m) acc[m] = zero4;
#pragma unroll
    for (int kk = 0; kk < 6; ++kk) {
      b16x8 bw = *(const b16x8*)(WkvB + col * CDIM + kk * 32 + lg * 8);
#pragma unroll
      for (int m = 0; m < 4; ++m) {
        b16x8 a = *(const b16x8*)(SH + swz(m * 16 + l15, kk * 32 + lg * 8));
        acc[m] = MFMA(a, bw, acc[m]);
      }
    }
    const float bias = bkv[col];
    if (col < CDIM) {  // K half -> KH[token][col]
#pragma unroll
      for (int m = 0; m < 4; ++m)
#pragma unroll
        for (int r = 0; r < 4; ++r)
          KH[swz(m * 16 + lg * 4 + r, col)] = f2bf(acc[m][r] + bias);
    } else {  // V half -> VT[c][token]
      const int c = col - CDIM;
#pragma unroll
      for (int m = 0; m < 4; ++m) {
        b16x4 o = {f2bf(acc[m][0] + bias), f2bf(acc[m][1] + bias),
                   f2bf(acc[m][2] + bias), f2bf(acc[m][3] + bias)};
        *(b16x4*)(VT + c * 68 + m * 16 + lg * 4) = o;
      }
    }
  }
  __syncthreads();  // B4: kh/vT ready; SH kv dead -> P scratch

  // ---- attention (swapped QK, in-lane softmax): lane l15 owns q-row qc ----
  const float* maskw = maskg + (size_t)(b % nW) * (NTOK * NTOK);
  f32x4 maskv[3];
#pragma unroll
  for (int nt = 0; nt < 3; ++nt)
    maskv[nt] = *(const f32x4u*)(maskw + qc * NTOK + nt * 16 + lg * 4);
  const float mask48 = (lg == 0) ? maskw[qc * NTOK + 48] : 0.f;

  f32x4 xh[3][2];
#pragma unroll
  for (int hh = 0; hh < 3; ++hh) {
    xh[hh][0] = zero4;
    xh[hh][1] = zero4;
  }
#pragma unroll
  for (int hh = 0; hh < 3; ++hh) {
    const int h = h0 + hh;
    f32x4 Ls[4];
    __builtin_amdgcn_s_setprio(1);
#pragma unroll
    for (int nt = 0; nt < 4; ++nt) {
      b16x8 bk = *(const b16x8*)(KH + swz(nt * 16 + l15, h * 32 + lg * 8));
      Ls[nt] = MFMA(bk, aq[hh], zero4);  // swapped: D col = q-row l15
    }
    __builtin_amdgcn_s_setprio(0);
    // bias (k-padded -1e9) + window mask, all vectorized, no branches
    const float* bt = bias_t + (h * NTOK + qc) * 64;
#pragma unroll
    for (int nt = 0; nt < 4; ++nt) {
      f32x4 bb = *(const f32x4*)(bt + nt * 16 + lg * 4);
#pragma unroll
      for (int rr = 0; rr < 4; ++rr) Ls[nt][rr] += bb[rr];
    }
#pragma unroll
    for (int nt = 0; nt < 3; ++nt)
#pragma unroll
      for (int rr = 0; rr < 4; ++rr) Ls[nt][rr] += maskv[nt][rr];
    Ls[3][0] += mask48;  // k=48 (lg==0); other lanes add 0, k>=49 has -1e9 bias

    // in-lane softmax: 15 fmax + shfl(16,32); row lives in this lane
    float mx = Ls[0][0];
#pragma unroll
    for (int nt = 0; nt < 4; ++nt)
#pragma unroll
      for (int rr = 0; rr < 4; ++rr) mx = fmaxf(mx, Ls[nt][rr]);
    mx = fmaxf(mx, __shfl_xor(mx, 16));
    mx = fmaxf(mx, __shfl_xor(mx, 32));
    float sum = 0.f;
#pragma unroll
    for (int nt = 0; nt < 4; ++nt)
#pragma unroll
      for (int rr = 0; rr < 4; ++rr) {
        Ls[nt][rr] = __expf(Ls[nt][rr] - mx);
        sum += Ls[nt][rr];
      }
    sum += __shfl_xor(sum, 16);
    sum += __shfl_xor(sum, 32);
    const float inv = 1.f / sum;

    // P -> per-wave scratch in dead-SH (ps swizzle), two 32-k halves; PV
    short* Pscr = SH + w * 512;
    b16x8 ap[2];
#pragma unroll
    for (int kkh = 0; kkh < 2; ++kkh) {
#pragma unroll
      for (int nth = 0; nth < 2; ++nth) {
        const int nt = 2 * kkh + nth;
        b16x4 o = {f2bf(Ls[nt][0] * inv), f2bf(Ls[nt][1] * inv),
                   f2bf(Ls[nt][2] * inv), f2bf(Ls[nt][3] * inv)};
        *(b16x4*)(Pscr + ps(l15, nth * 16 + lg * 4)) = o;
      }
      ap[kkh] = *(const b16x8*)(Pscr + ps(l15, lg * 8));
    }
    __builtin_amdgcn_s_setprio(1);
#pragma unroll
    for (int kkh = 0; kkh < 2; ++kkh)
#pragma unroll
      for (int nv = 0; nv < 2; ++nv) {
        b16x8 bv = *(const b16x8*)(VT + (h * 32 + nv * 16 + l15) * 68 + kkh * 32 + lg * 8);
        xh[hh][nv] = MFMA(ap[kkh], bv, xh[hh][nv]);
      }
    __builtin_amdgcn_s_setprio(0);
  }
  __syncthreads();  // B5: all KH/VT/SH-P reads done
  // ---- x -> KH ----
#pragma unroll
  for (int hh = 0; hh < 3; ++hh)
#pragma unroll
    for (int nv = 0; nv < 2; ++nv)
#pragma unroll
      for (int r = 0; r < 4; ++r)
        KH[swz(R * 16 + lg * 4 + r, (h0 + hh) * 32 + nv * 16 + l15)] =
            f2bf(xh[hh][nv][r]);
  __syncthreads();  // B6: x ready (SH, VT dead -> bounce region)

  // ---- output projection -> f32 bounce (stride 204) ----
#pragma unroll
  for (int t = 0; t < 6; ++t) {
    const int pid = w * 6 + t;
    const int j = pid >> 2, m = pid & 3;
    const int col = j * 16 + l15;
    f32x4 oacc = zero4;
#pragma unroll
    for (int kk = 0; kk < 6; ++kk) {
      b16x8 a = *(const b16x8*)(KH + swz(m * 16 + l15, kk * 32 + lg * 8));
      b16x8 bw = *(const b16x8*)(WoB + col * CDIM + kk * 32 + lg * 8);
      oacc = MFMA(a, bw, oacc);
    }
    const float bias = bo[col];
#pragma unroll
    for (int r = 0; r < 4; ++r) {
      const int row = m * 16 + lg * 4 + r;
      if (row < NTOK) BF[row * 204 + col] = oacc[r] + bias;
    }
  }
  __syncthreads();  // B7: bounce ready

  // ---- fully coalesced output stores (16B/lane contiguous) ----
  float* dst = outg + (size_t)b * (NTOK * CDIM);
#pragma unroll
  for (int t = 0; t < 5; ++t) {
    int idx = tid + t * 512;
    if (idx < NTOK * 48) {
      int row = idx / 48, c4 = idx % 48;
      f32x4 v = *(const f32x4*)(BF + row * 204 + c4 * 4);
      *(f32x4*)(dst + row * CDIM + c4 * 4) = v;
    }
  }
}

extern "C" void kernel_launch(void* const* d_in, const int* in_sizes, int n_in,
                              void* d_out, int out_size, void* d_ws, size_t ws_size,
                              hipStream_t stream) {
  const float* q = (const float*)d_in[0];
  const float* kv = (const float*)d_in[1];
  const float* mask = (const float*)d_in[2];
  const float* Wq = (const float*)d_in[3];
  const float* bq = (const float*)d_in[4];
  const float* Wkv = (const float*)d_in[5];
  const float* bkv = (const float*)d_in[6];
  const float* Wo = (const float*)d_in[7];
  const float* bo = (const float*)d_in[8];
  const float* rpb = (const float*)d_in[9];
  short* wsW = (short*)d_ws;
  float* bias_t = (float*)((char*)d_ws + 294912);  // [6][49][64] f32, 75264 B

  const int B = in_sizes[0] / (NTOK * CDIM);
  const int nW = in_sizes[2] / (NTOK * NTOK);

  const int prep_total = 147456 + NHEAD * NTOK * 64;
  prep_all<<<(prep_total + 255) / 256, 256, 0, stream>>>(Wq, Wkv, Wo, rpb, wsW,
                                                         bias_t);
  wmsa_kernel<<<B, 512, 0, stream>>>(q, kv, mask, bq, bkv, bo, wsW, bias_t,
                                     (float*)d_out, nW);
}